// Round 8
// baseline (26313.156 us; speedup 1.0000x reference)
//
#include <hip/hip_runtime.h>
#include <cstddef>
#include <cstdint>

// Pointer-network decoder, B=64, T=128, D=512, H=512.
// Round 8: ZERO grid barriers. One 512-thread block per batch runs all 128
// steps privately (h/c/mask/sel in LDS+regs). Cost: weights re-streamed from
// L2 each step (shared by the 8 blocks/XCD). No cross-block state at all.

#define NEGV (-1e9f)

static constexpr int T = 128;

// ---- workspace layout (element offsets, fp32) — identical to round 7 ----
static constexpr size_t OFF_X0W  = 512 + 5*64*512 + 64;       // [2048] (state slots unused now)
static constexpr size_t OFF_XW   = OFF_X0W  + 2048;           // [8192][2048]
static constexpr size_t OFF_CTX  = OFF_XW   + (size_t)8192*2048; // [8192][512]
static constexpr size_t OFF_CWO  = OFF_CTX  + (size_t)8192*512;  // [8192][512]

__device__ __forceinline__ float sigf(float x) { return 1.0f / (1.0f + expf(-x)); }

// ---------------- precompute: x0 row ----------------
__global__ __launch_bounds__(256) void x0w_kernel(
    const float* __restrict__ input0, const float* __restrict__ W_ih,
    const float* __restrict__ b_ih, const float* __restrict__ b_hh,
    float* __restrict__ x0w) {
  int wid = (blockIdx.x * 256 + threadIdx.x) >> 6;
  int l = threadIdx.x & 63;
  const float* wr = W_ih + (size_t)wid * 512;
  float acc = 0.f;
  #pragma unroll
  for (int q = 0; q < 8; ++q) acc += input0[l*8+q] * wr[l*8+q];
  #pragma unroll
  for (int off = 32; off; off >>= 1) acc += __shfl_xor(acc, off, 64);
  if (l == 0) x0w[wid] = acc + b_ih[wid] + b_hh[wid];
}

// ---------------- precompute: tiled fp32 GEMM, C = A@B^T + bias1 + bias2 ----------------
__global__ __launch_bounds__(256) void gemm_abt(
    const float* __restrict__ A, const float* __restrict__ Bm,
    const float* __restrict__ bias1, const float* __restrict__ bias2,
    float* __restrict__ C, int M, int N, int K, int ldb) {
  __shared__ float As[16][132];
  __shared__ float Bs[16][132];
  const int t = threadIdx.x;
  const int tx = t & 15, ty = t >> 4;
  const int mbase = blockIdx.y * 128, nbase = blockIdx.x * 128;
  float acc[8][8] = {};
  for (int kc = 0; kc < K; kc += 16) {
    __syncthreads();
    #pragma unroll
    for (int r = 0; r < 2; ++r) {
      int q = r * 256 + t;
      int row = q >> 2, kq = (q & 3) * 4;
      float4 va = *(const float4*)&A[(size_t)(mbase + row) * K + kc + kq];
      As[kq+0][row] = va.x; As[kq+1][row] = va.y; As[kq+2][row] = va.z; As[kq+3][row] = va.w;
      float4 vb = *(const float4*)&Bm[(size_t)(nbase + row) * ldb + kc + kq];
      Bs[kq+0][row] = vb.x; Bs[kq+1][row] = vb.y; Bs[kq+2][row] = vb.z; Bs[kq+3][row] = vb.w;
    }
    __syncthreads();
    #pragma unroll
    for (int kk = 0; kk < 16; ++kk) {
      float a[8], b[8];
      *(float4*)(a)   = *(const float4*)&As[kk][ty*8];
      *(float4*)(a+4) = *(const float4*)&As[kk][ty*8+4];
      *(float4*)(b)   = *(const float4*)&Bs[kk][tx*8];
      *(float4*)(b+4) = *(const float4*)&Bs[kk][tx*8+4];
      #pragma unroll
      for (int i = 0; i < 8; ++i)
        #pragma unroll
        for (int j = 0; j < 8; ++j)
          acc[i][j] = fmaf(a[i], b[j], acc[i][j]);
    }
  }
  float bv[8];
  #pragma unroll
  for (int q = 0; q < 8; ++q) {
    int n = nbase + tx*8 + q;
    bv[q] = (bias1 ? bias1[n] : 0.f) + (bias2 ? bias2[n] : 0.f);
  }
  #pragma unroll
  for (int i = 0; i < 8; ++i) {
    size_t m = (size_t)(mbase + ty*8 + i);
    float4 o0 = make_float4(acc[i][0]+bv[0], acc[i][1]+bv[1], acc[i][2]+bv[2], acc[i][3]+bv[3]);
    float4 o1 = make_float4(acc[i][4]+bv[4], acc[i][5]+bv[5], acc[i][6]+bv[6], acc[i][7]+bv[7]);
    *(float4*)&C[m * N + nbase + tx*8]     = o0;
    *(float4*)&C[m * N + nbase + tx*8 + 4] = o1;
  }
}

// ---------------- the per-batch decoder: 1 block = 1 batch, no grid sync ----------------
__global__ __launch_bounds__(512) void decoder_kernel(
    const float* __restrict__ h0, const float* __restrict__ c0,
    const float* __restrict__ cmask,
    const float* __restrict__ W_hh,
    const float* __restrict__ W_inp, const float* __restrict__ b_inp_,
    const float* __restrict__ W_out, const float* __restrict__ b_out_,
    const float* __restrict__ vvec,
    float* __restrict__ ws, float* __restrict__ out) {
  __shared__ float sh[512];      // h state
  __shared__ float sc[512];      // c state
  __shared__ float shl[512];     // h_lstm
  __shared__ float sinp[512];    // W_inp h_lstm + b_inp
  __shared__ float sv[512];      // v vector
  __shared__ float sscore[128];  // masked scores
  __shared__ float salpha[128];  // softmax
  __shared__ float smask[128];   // running mask
  __shared__ float s_mlen;
  __shared__ int   ssel;

  const float* x0wp = ws + OFF_X0W;
  const float* xwp  = ws + OFF_XW;
  const float* ctxp = ws + OFF_CTX;
  const float* cwop = ws + OFF_CWO;

  float* out_scores = out;
  float* out_ptrs   = out + (size_t)64*128*128;
  float* out_hf     = out_ptrs + 64*128;
  float* out_cf     = out_hf + 64*512;

  const int b = blockIdx.x, t = threadIdx.x;

  // ---- init ----
  sh[t] = h0[(size_t)b*512 + t];
  sc[t] = c0[(size_t)b*512 + t];
  sv[t] = vvec[t];
  if (t < 128) smask[t] = cmask[b*128 + t];
  const float bi_r = b_inp_[t];
  const float bo_r = b_out_[t];
  __syncthreads();
  if (t < 64) {
    float m_ = smask[t] + smask[64 + t];
    #pragma unroll
    for (int off = 32; off; off >>= 1) m_ += __shfl_xor(m_, off, 64);
    if (t == 0) s_mlen = m_;
  }
  __syncthreads();

  const int tc = t >> 2, ksl = t & 3;   // e-phase mapping
  const float* ctx_r = ctxp + ((size_t)(b*128 + tc))*512;

  for (int s = 0; s < T; ++s) {
    // ====== PHASE A: gates -> c_t, h_lstm ======
    // Thread t owns gate rows {t, 512+t, 1024+t, 1536+t} = the 4 gates of
    // hidden unit t. Row streamed with float4; accumulators stay in regs.
    float acc[4];
    #pragma unroll
    for (int p = 0; p < 4; ++p) {
      const float* wr = W_hh + (size_t)(p*512 + t) * 512;
      float a0 = 0.f, a1 = 0.f;
      #pragma unroll 8
      for (int j = 0; j < 512; j += 8) {
        float4 w0 = *(const float4*)&wr[j];
        float4 w1 = *(const float4*)&wr[j+4];
        float4 h0v = *(const float4*)&sh[j];
        float4 h1v = *(const float4*)&sh[j+4];
        a0 = fmaf(h0v.x, w0.x, fmaf(h0v.y, w0.y,
             fmaf(h0v.z, w0.z, fmaf(h0v.w, w0.w, a0))));
        a1 = fmaf(h1v.x, w1.x, fmaf(h1v.y, w1.y,
             fmaf(h1v.z, w1.z, fmaf(h1v.w, w1.w, a1))));
      }
      acc[p] = a0 + a1;
    }
    {
      const float* xrow = (s == 0) ? x0wp
                        : (xwp + ((size_t)b*128 + (size_t)ssel) * 2048);
      float gi = acc[0] + xrow[t];
      float gf = acc[1] + xrow[512 + t];
      float gg = acc[2] + xrow[1024 + t];
      float go = acc[3] + xrow[1536 + t];
      float ct = sigf(gf)*sc[t] + sigf(gi)*tanhf(gg);
      sc[t] = ct;                           // own slot
      shl[t] = sigf(go)*tanhf(ct);
    }
    __syncthreads();

    // ====== PHASE B: inp = hl@W_inp^T + b_inp ; hw = hl@Wout2^T + b_out ======
    float hw_r;
    {
      const float* wi = W_inp + (size_t)t * 512;
      const float* wo = W_out + (size_t)t * 1024 + 512;
      float i0 = 0.f, i1 = 0.f, o0 = 0.f, o1 = 0.f;
      #pragma unroll 8
      for (int j = 0; j < 512; j += 8) {
        float4 wiv0 = *(const float4*)&wi[j];
        float4 wiv1 = *(const float4*)&wi[j+4];
        float4 h0v = *(const float4*)&shl[j];
        float4 h1v = *(const float4*)&shl[j+4];
        i0 = fmaf(h0v.x, wiv0.x, fmaf(h0v.y, wiv0.y,
             fmaf(h0v.z, wiv0.z, fmaf(h0v.w, wiv0.w, i0))));
        i1 = fmaf(h1v.x, wiv1.x, fmaf(h1v.y, wiv1.y,
             fmaf(h1v.z, wiv1.z, fmaf(h1v.w, wiv1.w, i1))));
      }
      #pragma unroll 8
      for (int j = 0; j < 512; j += 8) {
        float4 wov0 = *(const float4*)&wo[j];
        float4 wov1 = *(const float4*)&wo[j+4];
        float4 h0v = *(const float4*)&shl[j];
        float4 h1v = *(const float4*)&shl[j+4];
        o0 = fmaf(h0v.x, wov0.x, fmaf(h0v.y, wov0.y,
             fmaf(h0v.z, wov0.z, fmaf(h0v.w, wov0.w, o0))));
        o1 = fmaf(h1v.x, wov1.x, fmaf(h1v.y, wov1.y,
             fmaf(h1v.z, wov1.z, fmaf(h1v.w, wov1.w, o1))));
      }
      sinp[t] = (i0 + i1) + bi_r;
      hw_r = (o0 + o1) + bo_r;
    }
    __syncthreads();

    // ====== PHASE E: e[tc] = sum_k v[k]*tanh(ctx[tc,k] + inp[k]) ======
    {
      float ea = 0.f;
      #pragma unroll 8
      for (int j = 0; j < 128; ++j) {
        const int k = (j << 2) | ksl;
        ea = fmaf(sv[k], tanhf(ctx_r[k] + sinp[k]), ea);
      }
      ea += __shfl_xor(ea, 1, 64);
      ea += __shfl_xor(ea, 2, 64);
      if (ksl == 0) {
        float scv = (smask[tc] > 0.f) ? ea : NEGV;
        sscore[tc] = scv;
        out_scores[((size_t)b*128 + s)*128 + tc] = scv;
      }
    }
    __syncthreads();

    // ====== PHASE SM: softmax + selection (wave 0) ======
    if (t < 64) {
      float s0 = sscore[t], s1 = sscore[64 + t];
      float mx = fmaxf(s0, s1);
      #pragma unroll
      for (int off = 32; off; off >>= 1) mx = fmaxf(mx, __shfl_xor(mx, off, 64));
      float x0 = expf(s0 - mx), x1 = expf(s1 - mx);
      float sum = x0 + x1;
      #pragma unroll
      for (int off = 32; off; off >>= 1) sum += __shfl_xor(sum, off, 64);
      float a0 = x0 / sum, a1 = x1 / sum;
      salpha[t] = a0; salpha[64 + t] = a1;
      float p0 = a0 * smask[t], p1 = a1 * smask[64 + t];
      float pv; int pi;
      if (p1 > p0) { pv = p1; pi = t + 64; } else { pv = p0; pi = t; }
      #pragma unroll
      for (int off = 32; off; off >>= 1) {
        float ov = __shfl_xor(pv, off, 64);
        int   oi = __shfl_xor(pi, off, 64);
        if (ov > pv || (ov == pv && oi < pi)) { pv = ov; pi = oi; }
      }
      if (t == 0) {
        int se = (s_mlen > (float)s) ? pi : s;
        ssel = se;
        smask[se] = 0.f;
        out_ptrs[b*128 + s] = (float)se;
      }
    }
    __syncthreads();

    // ====== PHASE ATTN: h_t = tanh(hw + sum_tc alpha[tc]*cwo[tc, t]) ======
    {
      const float* cw = cwop + (size_t)b*128*512 + t;
      float ax0 = 0.f, ax1 = 0.f, ax2 = 0.f, ax3 = 0.f;
      #pragma unroll 8
      for (int q = 0; q < 128; q += 4) {
        ax0 = fmaf(salpha[q+0], cw[(size_t)(q+0)*512], ax0);
        ax1 = fmaf(salpha[q+1], cw[(size_t)(q+1)*512], ax1);
        ax2 = fmaf(salpha[q+2], cw[(size_t)(q+2)*512], ax2);
        ax3 = fmaf(salpha[q+3], cw[(size_t)(q+3)*512], ax3);
      }
      float hn = tanhf(hw_r + ((ax0 + ax1) + (ax2 + ax3)));
      sh[t] = hn;                          // A-reads of sh long past (3 syncs)
    }
    __syncthreads();
  }

  // ---- epilogue ----
  out_hf[(size_t)b*512 + t] = sh[t];
  out_cf[(size_t)b*512 + t] = sc[t];
}

extern "C" void kernel_launch(void* const* d_in, const int* in_sizes, int n_in,
                              void* d_out, int out_size, void* d_ws, size_t ws_size,
                              hipStream_t stream) {
  (void)in_sizes; (void)n_in; (void)out_size; (void)ws_size;
  const float* inputs    = (const float*)d_in[0];
  const float* h0        = (const float*)d_in[1];
  const float* c0        = (const float*)d_in[2];
  const float* candidate = (const float*)d_in[3];
  const float* cmask     = (const float*)d_in[4];
  const float* input0    = (const float*)d_in[5];
  const float* W_ih      = (const float*)d_in[6];
  const float* b_ih      = (const float*)d_in[7];
  const float* W_hh      = (const float*)d_in[8];
  const float* b_hh      = (const float*)d_in[9];
  const float* W_out     = (const float*)d_in[10];
  const float* b_out     = (const float*)d_in[11];
  const float* W_inp     = (const float*)d_in[12];
  const float* b_inp     = (const float*)d_in[13];
  const float* W_ctx     = (const float*)d_in[14];
  const float* b_ctx     = (const float*)d_in[15];
  const float* v         = (const float*)d_in[16];
  float* ws  = (float*)d_ws;
  float* outp = (float*)d_out;

  // x0 row: input0 @ W_ih^T + b_ih + b_hh
  x0w_kernel<<<512, 256, 0, stream>>>(input0, W_ih, b_ih, b_hh, ws + OFF_X0W);

  // xW table: inputs(8192,512) @ W_ih(2048,512)^T + b_ih + b_hh
  gemm_abt<<<dim3(16, 64), 256, 0, stream>>>(inputs, W_ih, b_ih, b_hh,
                                             ws + OFF_XW, 8192, 2048, 512, 512);
  // ctx_lin: candidate(8192,512) @ W_ctx(512,512)^T + b_ctx
  gemm_abt<<<dim3(4, 64), 256, 0, stream>>>(candidate, W_ctx, b_ctx, nullptr,
                                            ws + OFF_CTX, 8192, 512, 512, 512);
  // ctxWo: ctx_lin @ W_out[:, :512]^T   (W_out row stride 1024)
  gemm_abt<<<dim3(4, 64), 256, 0, stream>>>(ws + OFF_CTX, W_out, nullptr, nullptr,
                                            ws + OFF_CWO, 8192, 512, 512, 1024);

  decoder_kernel<<<64, 512, 0, stream>>>(h0, c0, cmask, W_hh, W_inp, b_inp,
                                         W_out, b_out, v, ws, outp);
}